// Round 1
// baseline (256.078 us; speedup 1.0000x reference)
//
#include <hip/hip_runtime.h>
#include <hip/hip_bf16.h>

typedef __attribute__((ext_vector_type(8))) short short8;
typedef __attribute__((ext_vector_type(4))) float f32x4;

constexpr int BM = 128, BN = 128, BK = 64, PAD = 8;  // PAD=8 shorts=16B keeps 16B alignment, 2-way-free banks

__device__ __forceinline__ ushort f2b(float f) {
    __hip_bfloat16 h = __float2bfloat16(f);
    return *reinterpret_cast<ushort*>(&h);
}
__device__ __forceinline__ float b2f(ushort u) {
    return __uint_as_float(((unsigned)u) << 16);
}

// stage a 128xBK fp32 tile -> bf16 LDS
__device__ __forceinline__ void stage_f32(const float* __restrict__ src, int ld,
                                          ushort dst[][BK + PAD], int tid) {
    int vec = tid & 15, row = tid >> 4;          // 16 float4 per row, 16 rows/pass
#pragma unroll
    for (int p = 0; p < 8; ++p, row += 16) {
        float4 v = *reinterpret_cast<const float4*>(src + (size_t)row * ld + vec * 4);
        ushort4 o;
        o.x = f2b(v.x); o.y = f2b(v.y); o.z = f2b(v.z); o.w = f2b(v.w);
        *reinterpret_cast<ushort4*>(&dst[row][vec * 4]) = o;
    }
}

// stage a 128xBK bf16 tile -> LDS (raw copy)
__device__ __forceinline__ void stage_bf16(const ushort* __restrict__ src, int ld,
                                           ushort dst[][BK + PAD], int tid) {
    int vec = tid & 7, row = tid >> 3;           // 8 short8 per row, 32 rows/pass
#pragma unroll
    for (int p = 0; p < 4; ++p, row += 32) {
        uint4 v = *reinterpret_cast<const uint4*>(src + (size_t)row * ld + vec * 8);
        *reinterpret_cast<uint4*>(&dst[row][vec * 8]) = v;
    }
}

// C[m][n] = scale * sum_k A[m][k]*B[n][k] (+ bias[n]) ; optional causal mask / triangular K-clip
template <bool A_F32, bool B_F32, bool OUT_F32, bool CAUSAL, bool TRI, bool BIAS>
__global__ __launch_bounds__(256) void gemm_nt(
    const void* __restrict__ Ap, const void* __restrict__ Bp, void* __restrict__ Cp,
    const float* __restrict__ bias, int M, int N, int K, float scale,
    long sA, long sB, long sC) {
    __shared__ ushort As[BM][BK + PAD];
    __shared__ ushort Bs[BN][BK + PAD];

    const int tid = threadIdx.x;
    const int z = blockIdx.z;
    const int m0 = blockIdx.y * BM, n0 = blockIdx.x * BN;

    const float*  Af = (const float*)Ap + (size_t)z * sA;
    const ushort* Au = (const ushort*)Ap + (size_t)z * sA;
    const float*  Bf = (const float*)Bp + (size_t)z * sB;
    const ushort* Bu = (const ushort*)Bp + (size_t)z * sB;
    float*  Cf = (float*)Cp + (size_t)z * sC;
    ushort* Cu = (ushort*)Cp + (size_t)z * sC;

    const int lane = tid & 63, wave = tid >> 6;
    const int wm = (wave >> 1) * 64, wn = (wave & 1) * 64;
    const int lr = lane & 15, lk = (lane >> 4) * 8;

    f32x4 acc[4][4] = {};

    const bool skip = CAUSAL && (n0 >= m0 + BM);  // fully-masked tile
    if (!skip) {
        int ktiles = K / BK;
        if (TRI) {
            int kt2 = (m0 + BM) / BK;
            if (kt2 < ktiles) ktiles = kt2;
        }
        for (int kt = 0; kt < ktiles; ++kt) {
            const int k0 = kt * BK;
            if constexpr (A_F32) stage_f32(Af + (size_t)m0 * K + k0, K, As, tid);
            else                 stage_bf16(Au + (size_t)m0 * K + k0, K, As, tid);
            if constexpr (B_F32) stage_f32(Bf + (size_t)n0 * K + k0, K, Bs, tid);
            else                 stage_bf16(Bu + (size_t)n0 * K + k0, K, Bs, tid);
            __syncthreads();
#pragma unroll
            for (int kk = 0; kk < BK / 32; ++kk) {
                short8 a[4], b[4];
#pragma unroll
                for (int i = 0; i < 4; ++i)
                    a[i] = *reinterpret_cast<const short8*>(&As[wm + i * 16 + lr][kk * 32 + lk]);
#pragma unroll
                for (int j = 0; j < 4; ++j)
                    b[j] = *reinterpret_cast<const short8*>(&Bs[wn + j * 16 + lr][kk * 32 + lk]);
#pragma unroll
                for (int i = 0; i < 4; ++i)
#pragma unroll
                    for (int j = 0; j < 4; ++j)
                        acc[i][j] = __builtin_amdgcn_mfma_f32_16x16x32_bf16(a[i], b[j], acc[i][j], 0, 0, 0);
            }
            __syncthreads();
        }
    }

    // epilogue: D col = lane&15, row = (lane>>4)*4 + r
    const int r4 = (lane >> 4) * 4;
#pragma unroll
    for (int i = 0; i < 4; ++i) {
#pragma unroll
        for (int j = 0; j < 4; ++j) {
            const int gc = n0 + wn + j * 16 + lr;
            const float badd = BIAS ? bias[gc] : 0.f;
#pragma unroll
            for (int r = 0; r < 4; ++r) {
                const int gr = m0 + wm + i * 16 + r4 + r;
                float v = acc[i][j][r] * scale + badd;
                if (CAUSAL && gc > gr) v = -INFINITY;
                if constexpr (OUT_F32) Cf[(size_t)gr * N + gc] = v;
                else                   Cu[(size_t)gr * N + gc] = f2b(v);
            }
        }
    }
}

// row softmax over T=2048 bf16 entries, in place; -inf entries -> 0
__global__ __launch_bounds__(256) void softmax_rows(ushort* __restrict__ S, int T) {
    const size_t row = blockIdx.x;
    ushort* p = S + row * (size_t)T;
    const int tid = threadIdx.x;
    const int lane = tid & 63, wave = tid >> 6;

    uint4 raw = *reinterpret_cast<const uint4*>(p + tid * 8);
    ushort* rs = reinterpret_cast<ushort*>(&raw);
    float f[8];
#pragma unroll
    for (int j = 0; j < 8; ++j) f[j] = b2f(rs[j]);

    float mx = f[0];
#pragma unroll
    for (int j = 1; j < 8; ++j) mx = fmaxf(mx, f[j]);
#pragma unroll
    for (int o = 32; o > 0; o >>= 1) mx = fmaxf(mx, __shfl_xor(mx, o));

    __shared__ float redm[4], reds[4];
    if (lane == 0) redm[wave] = mx;
    __syncthreads();
    mx = fmaxf(fmaxf(redm[0], redm[1]), fmaxf(redm[2], redm[3]));

    float e[8], s = 0.f;
#pragma unroll
    for (int j = 0; j < 8; ++j) { e[j] = __expf(f[j] - mx); s += e[j]; }
#pragma unroll
    for (int o = 32; o > 0; o >>= 1) s += __shfl_xor(s, o);
    if (lane == 0) reds[wave] = s;
    __syncthreads();
    s = reds[0] + reds[1] + reds[2] + reds[3];

    const float inv = 1.f / s;
    ushort outv[8];
#pragma unroll
    for (int j = 0; j < 8; ++j) outv[j] = f2b(e[j] * inv);
    *reinterpret_cast<uint4*>(p + tid * 8) = *reinterpret_cast<uint4*>(outv);
}

// per-batch bf16 transpose: Vt[c][s] = V[s][c], V is RxCc
__global__ __launch_bounds__(256) void transpose_bf16(const ushort* __restrict__ V,
                                                      ushort* __restrict__ Vt, int R, int Cc) {
    __shared__ ushort t[64][64 + 8];
    const int z = blockIdx.z;
    const ushort* src = V + (size_t)z * R * Cc;
    ushort* dst = Vt + (size_t)z * R * Cc;
    const int r0 = blockIdx.y * 64, c0 = blockIdx.x * 64;
    const int tid = threadIdx.x;
    const int vec = tid & 7, row = tid >> 3;
#pragma unroll
    for (int p = 0; p < 2; ++p) {
        const int r = row + p * 32;
        uint4 v = *reinterpret_cast<const uint4*>(src + (size_t)(r0 + r) * Cc + c0 + vec * 8);
        *reinterpret_cast<uint4*>(&t[r][vec * 8]) = v;
    }
    __syncthreads();
#pragma unroll
    for (int p = 0; p < 2; ++p) {
        const int r = row + p * 32;  // output row within tile = column of V
        ushort tmp[8];
#pragma unroll
        for (int j = 0; j < 8; ++j) tmp[j] = t[vec * 8 + j][r];
        *reinterpret_cast<uint4*>(dst + (size_t)(c0 + r) * R + r0 + vec * 8) =
            *reinterpret_cast<uint4*>(tmp);
    }
}

extern "C" void kernel_launch(void* const* d_in, const int* in_sizes, int n_in,
                              void* d_out, int out_size, void* d_ws, size_t ws_size,
                              hipStream_t stream) {
    const float* x  = (const float*)d_in[0];
    const float* Wk = (const float*)d_in[1];
    const float* bk = (const float*)d_in[2];
    const float* Wq = (const float*)d_in[3];
    const float* bq = (const float*)d_in[4];
    const float* Wv = (const float*)d_in[5];
    const float* bv = (const float*)d_in[6];
    float* out = (float*)d_out;

    constexpr int B = 4, T = 2048, C = 1024;
    constexpr size_t BTC = (size_t)B * T * C;       // 8388608

    ushort* Kb = (ushort*)d_ws;
    ushort* Qb = Kb + BTC;
    ushort* Vb = Qb + BTC;
    ushort* Vt = Vb + BTC;
    ushort* Sb = Vt + BTC;                           // B*T*T bf16

    dim3 blk(256);

    // 1) QKV projections: [B*T, C] = x @ W^T + b   (fp32 in -> bf16 out)
    dim3 gq(C / BN, (B * T) / BM, 1);
    gemm_nt<true, true, false, false, false, true><<<gq, blk, 0, stream>>>(
        x, Wk, Kb, bk, B * T, C, C, 1.f, 0, 0, 0);
    gemm_nt<true, true, false, false, false, true><<<gq, blk, 0, stream>>>(
        x, Wq, Qb, bq, B * T, C, C, 1.f, 0, 0, 0);
    gemm_nt<true, true, false, false, false, true><<<gq, blk, 0, stream>>>(
        x, Wv, Vb, bv, B * T, C, C, 1.f, 0, 0, 0);

    // 2) V transpose per batch: Vt[c][s]
    transpose_bf16<<<dim3(C / 64, T / 64, B), blk, 0, stream>>>(Vb, Vt, T, C);

    // 3) scores: S = Q K^T * C^-0.5, causal-masked (bf16)
    gemm_nt<false, false, false, true, false, false><<<dim3(T / BN, T / BM, B), blk, 0, stream>>>(
        Qb, Kb, Sb, nullptr, T, T, C, 0.03125f, (long)T * C, (long)T * C, (long)T * T);

    // 4) row softmax in place
    softmax_rows<<<dim3(B * T), blk, 0, stream>>>(Sb, T);

    // 5) y = P @ V  via NT gemm with Vt; K-loop clipped to causal extent; fp32 out
    gemm_nt<false, false, true, false, true, false><<<dim3(C / BN, T / BM, B), blk, 0, stream>>>(
        Sb, Vt, out, nullptr, T, C, T, 1.f, (long)T * T, (long)C * T, (long)T * C);
}

// Round 2
// 224.072 us; speedup vs baseline: 1.1428x; 1.1428x over previous
//
#include <hip/hip_runtime.h>
#include <hip/hip_bf16.h>

typedef __attribute__((ext_vector_type(8))) short short8;
typedef __attribute__((ext_vector_type(4))) float f32x4;

constexpr int BM = 128, BN = 128, BK = 64;

__device__ __forceinline__ ushort f2b(float f) {
    __hip_bfloat16 h = __float2bfloat16(f);
    return *reinterpret_cast<ushort*>(&h);
}
__device__ __forceinline__ float b2f(ushort u) {
    return __uint_as_float(((unsigned)u) << 16);
}

// async 16B/lane global->LDS. lds base must be wave-uniform; HW adds lane*16B.
__device__ __forceinline__ void gload_lds16(const ushort* g, ushort* l) {
    __builtin_amdgcn_global_load_lds(
        (const __attribute__((address_space(1))) void*)g,
        (__attribute__((address_space(3))) void*)l, 16, 0, 0);
}

// stage BM x BK bf16 tile (row-major, ld elems) into linear LDS [BM][BK]
__device__ __forceinline__ void stage_async(const ushort* __restrict__ src, int ld,
                                            ushort* lds, int tid) {
    const int wave = tid >> 6, lane = tid & 63;
#pragma unroll
    for (int p = 0; p < 4; ++p) {
        const int seg = p * 4 + wave;                 // 16 segments of 8 rows
        const int row = seg * 8 + (lane >> 3);
        const ushort* g = src + (size_t)row * ld + (lane & 7) * 8;
        gload_lds16(g, lds + seg * 512);              // seg*512 ush = seg*1024B, wave-uniform
    }
}

// ---- fused QKV projection: O_z[m][n] = sum_k xb[m][k]*W_z[n][k] + b_z[n] (bf16 out)
__global__ __launch_bounds__(256) void qkv_gemm(
    const ushort* __restrict__ xb,
    const ushort* __restrict__ W0, const ushort* __restrict__ W1, const ushort* __restrict__ W2,
    const float* __restrict__ b0, const float* __restrict__ b1, const float* __restrict__ b2,
    ushort* __restrict__ O0, ushort* __restrict__ O1, ushort* __restrict__ O2,
    int M, int N, int K) {
    __shared__ ushort As[BM * BK];
    __shared__ ushort Bs[BN * BK];

    const int tid = threadIdx.x, z = blockIdx.z;
    const int m0 = blockIdx.y * BM, n0 = blockIdx.x * BN;
    const ushort* W = (z == 0) ? W0 : (z == 1) ? W1 : W2;
    const float* bias = (z == 0) ? b0 : (z == 1) ? b1 : b2;
    ushort* O = (z == 0) ? O0 : (z == 1) ? O1 : O2;

    const int lane = tid & 63, wave = tid >> 6;
    const int wm = (wave >> 1) * 64, wn = (wave & 1) * 64;
    const int lr = lane & 15, lk = (lane >> 4) * 8;

    f32x4 acc[4][4] = {};

    for (int k0 = 0; k0 < K; k0 += BK) {
        stage_async(xb + (size_t)m0 * K + k0, K, As, tid);
        stage_async(W + (size_t)n0 * K + k0, K, Bs, tid);
        __syncthreads();
#pragma unroll
        for (int kk = 0; kk < BK / 32; ++kk) {
            short8 a[4], b[4];
#pragma unroll
            for (int i = 0; i < 4; ++i)
                a[i] = *reinterpret_cast<const short8*>(&As[(wm + i * 16 + lr) * BK + kk * 32 + lk]);
#pragma unroll
            for (int j = 0; j < 4; ++j)
                b[j] = *reinterpret_cast<const short8*>(&Bs[(wn + j * 16 + lr) * BK + kk * 32 + lk]);
#pragma unroll
            for (int i = 0; i < 4; ++i)
#pragma unroll
                for (int j = 0; j < 4; ++j)
                    acc[i][j] = __builtin_amdgcn_mfma_f32_16x16x32_bf16(a[i], b[j], acc[i][j], 0, 0, 0);
        }
        __syncthreads();
    }

    const int r4 = (lane >> 4) * 4;
#pragma unroll
    for (int i = 0; i < 4; ++i)
#pragma unroll
        for (int j = 0; j < 4; ++j) {
            const int gc = n0 + wn + j * 16 + lr;
            const float badd = bias[gc];
#pragma unroll
            for (int r = 0; r < 4; ++r) {
                const int gr = m0 + wm + i * 16 + r4 + r;
                O[(size_t)gr * N + gc] = f2b(acc[i][j][r] + badd);
            }
        }
}

// ---- generic batched NT gemm, bf16 in: C[m][n] = scale*sum_k A[m][k]*B[n][k]
template <bool OUT_F32, bool CAUSAL, bool TRI>
__global__ __launch_bounds__(256) void gemm_bt(
    const ushort* __restrict__ Ap, const ushort* __restrict__ Bp, void* __restrict__ Cp,
    int M, int N, int K, float scale, long sA, long sB, long sC) {
    __shared__ ushort As[BM * BK];
    __shared__ ushort Bs[BN * BK];

    const int tid = threadIdx.x, z = blockIdx.z;
    const int m0 = blockIdx.y * BM, n0 = blockIdx.x * BN;
    const ushort* A = Ap + (size_t)z * sA;
    const ushort* B = Bp + (size_t)z * sB;
    float* Cf = (float*)Cp + (size_t)z * sC;
    ushort* Cu = (ushort*)Cp + (size_t)z * sC;

    const int lane = tid & 63, wave = tid >> 6;
    const int wm = (wave >> 1) * 64, wn = (wave & 1) * 64;
    const int lr = lane & 15, lk = (lane >> 4) * 8;

    f32x4 acc[4][4] = {};

    const bool skip = CAUSAL && (n0 >= m0 + BM);
    if (!skip) {
        int ktiles = K / BK;
        if (TRI) {
            int kt2 = (m0 + BM) / BK;
            if (kt2 < ktiles) ktiles = kt2;
        }
        for (int kt = 0; kt < ktiles; ++kt) {
            const int k0 = kt * BK;
            stage_async(A + (size_t)m0 * K + k0, K, As, tid);
            stage_async(B + (size_t)n0 * K + k0, K, Bs, tid);
            __syncthreads();
#pragma unroll
            for (int kk = 0; kk < BK / 32; ++kk) {
                short8 a[4], b[4];
#pragma unroll
                for (int i = 0; i < 4; ++i)
                    a[i] = *reinterpret_cast<const short8*>(&As[(wm + i * 16 + lr) * BK + kk * 32 + lk]);
#pragma unroll
                for (int j = 0; j < 4; ++j)
                    b[j] = *reinterpret_cast<const short8*>(&Bs[(wn + j * 16 + lr) * BK + kk * 32 + lk]);
#pragma unroll
                for (int i = 0; i < 4; ++i)
#pragma unroll
                    for (int j = 0; j < 4; ++j)
                        acc[i][j] = __builtin_amdgcn_mfma_f32_16x16x32_bf16(a[i], b[j], acc[i][j], 0, 0, 0);
            }
            __syncthreads();
        }
    }

    const int r4 = (lane >> 4) * 4;
#pragma unroll
    for (int i = 0; i < 4; ++i)
#pragma unroll
        for (int j = 0; j < 4; ++j) {
            const int gc = n0 + wn + j * 16 + lr;
#pragma unroll
            for (int r = 0; r < 4; ++r) {
                const int gr = m0 + wm + i * 16 + r4 + r;
                float v = acc[i][j][r] * scale;
                if (CAUSAL && gc > gr) v = -INFINITY;
                if constexpr (OUT_F32) Cf[(size_t)gr * N + gc] = v;
                else                   Cu[(size_t)gr * N + gc] = f2b(v);
            }
        }
}

// ---- fp32 -> bf16 convert, 8 elems/thread
__global__ __launch_bounds__(256) void cvt_f32_bf16(const float* __restrict__ in,
                                                    ushort* __restrict__ out, int n8) {
    const int i = blockIdx.x * 256 + threadIdx.x;
    if (i >= n8) return;
    const float4* p = reinterpret_cast<const float4*>(in) + (size_t)i * 2;
    float4 a = p[0], b = p[1];
    ushort o[8] = {f2b(a.x), f2b(a.y), f2b(a.z), f2b(a.w),
                   f2b(b.x), f2b(b.y), f2b(b.z), f2b(b.w)};
    reinterpret_cast<uint4*>(out)[i] = *reinterpret_cast<uint4*>(o);
}

// ---- row softmax over T bf16 entries, in place; -inf -> 0
__global__ __launch_bounds__(256) void softmax_rows(ushort* __restrict__ S, int T) {
    const size_t row = blockIdx.x;
    ushort* p = S + row * (size_t)T;
    const int tid = threadIdx.x;
    const int lane = tid & 63, wave = tid >> 6;

    uint4 raw = *reinterpret_cast<const uint4*>(p + tid * 8);
    ushort* rs = reinterpret_cast<ushort*>(&raw);
    float f[8];
#pragma unroll
    for (int j = 0; j < 8; ++j) f[j] = b2f(rs[j]);

    float mx = f[0];
#pragma unroll
    for (int j = 1; j < 8; ++j) mx = fmaxf(mx, f[j]);
#pragma unroll
    for (int o = 32; o > 0; o >>= 1) mx = fmaxf(mx, __shfl_xor(mx, o));

    __shared__ float redm[4], reds[4];
    if (lane == 0) redm[wave] = mx;
    __syncthreads();
    mx = fmaxf(fmaxf(redm[0], redm[1]), fmaxf(redm[2], redm[3]));

    float e[8], s = 0.f;
#pragma unroll
    for (int j = 0; j < 8; ++j) { e[j] = __expf(f[j] - mx); s += e[j]; }
#pragma unroll
    for (int o = 32; o > 0; o >>= 1) s += __shfl_xor(s, o);
    if (lane == 0) reds[wave] = s;
    __syncthreads();
    s = reds[0] + reds[1] + reds[2] + reds[3];

    const float inv = 1.f / s;
    ushort outv[8];
#pragma unroll
    for (int j = 0; j < 8; ++j) outv[j] = f2b(e[j] * inv);
    *reinterpret_cast<uint4*>(p + tid * 8) = *reinterpret_cast<uint4*>(outv);
}

// ---- per-batch bf16 transpose: Vt[c][s] = V[s][c]
__global__ __launch_bounds__(256) void transpose_bf16(const ushort* __restrict__ V,
                                                      ushort* __restrict__ Vt, int R, int Cc) {
    __shared__ ushort t[64][64 + 8];
    const int z = blockIdx.z;
    const ushort* src = V + (size_t)z * R * Cc;
    ushort* dst = Vt + (size_t)z * R * Cc;
    const int r0 = blockIdx.y * 64, c0 = blockIdx.x * 64;
    const int tid = threadIdx.x;
    const int vec = tid & 7, row = tid >> 3;
#pragma unroll
    for (int p = 0; p < 2; ++p) {
        const int r = row + p * 32;
        uint4 v = *reinterpret_cast<const uint4*>(src + (size_t)(r0 + r) * Cc + c0 + vec * 8);
        *reinterpret_cast<uint4*>(&t[r][vec * 8]) = v;
    }
    __syncthreads();
#pragma unroll
    for (int p = 0; p < 2; ++p) {
        const int r = row + p * 32;
        ushort tmp[8];
#pragma unroll
        for (int j = 0; j < 8; ++j) tmp[j] = t[vec * 8 + j][r];
        *reinterpret_cast<uint4*>(dst + (size_t)(c0 + r) * R + r0 + vec * 8) =
            *reinterpret_cast<uint4*>(tmp);
    }
}

extern "C" void kernel_launch(void* const* d_in, const int* in_sizes, int n_in,
                              void* d_out, int out_size, void* d_ws, size_t ws_size,
                              hipStream_t stream) {
    const float* x  = (const float*)d_in[0];
    const float* Wk = (const float*)d_in[1];
    const float* bk = (const float*)d_in[2];
    const float* Wq = (const float*)d_in[3];
    const float* bq = (const float*)d_in[4];
    const float* Wv = (const float*)d_in[5];
    const float* bv = (const float*)d_in[6];
    float* out = (float*)d_out;

    constexpr int B = 4, T = 2048, C = 1024;
    constexpr size_t BTC = (size_t)B * T * C;        // 8388608

    ushort* Kb = (ushort*)d_ws;
    ushort* Qb = Kb + BTC;
    ushort* Vb = Qb + BTC;
    ushort* Vt = Vb + BTC;
    ushort* Sb = Vt + BTC;                            // B*T*T = 16777216 ush
    // aliased into Sb region (dead before the scores GEMM writes Sb):
    ushort* xb  = Sb;                                 // 8388608 ush
    ushort* Wkb = Sb + BTC;                           // 3 x 1048576 ush
    ushort* Wqb = Wkb + (size_t)C * C;
    ushort* Wvb = Wqb + (size_t)C * C;

    dim3 blk(256);

    // 0) fp32 -> bf16 converts
    cvt_f32_bf16<<<dim3((int)(BTC / 8 / 256)), blk, 0, stream>>>(x, xb, (int)(BTC / 8));
    cvt_f32_bf16<<<dim3(C * C / 8 / 256), blk, 0, stream>>>(Wk, Wkb, C * C / 8);
    cvt_f32_bf16<<<dim3(C * C / 8 / 256), blk, 0, stream>>>(Wq, Wqb, C * C / 8);
    cvt_f32_bf16<<<dim3(C * C / 8 / 256), blk, 0, stream>>>(Wv, Wvb, C * C / 8);

    // 1) fused QKV projections
    qkv_gemm<<<dim3(C / BN, (B * T) / BM, 3), blk, 0, stream>>>(
        xb, Wkb, Wqb, Wvb, bk, bq, bv, Kb, Qb, Vb, B * T, C, C);

    // 2) V transpose per batch
    transpose_bf16<<<dim3(C / 64, T / 64, B), blk, 0, stream>>>(Vb, Vt, T, C);

    // 3) scores: S = Q K^T * C^-0.5, causal-masked (bf16)
    gemm_bt<false, true, false><<<dim3(T / BN, T / BM, B), blk, 0, stream>>>(
        Qb, Kb, Sb, T, T, C, 0.03125f, (long)T * C, (long)T * C, (long)T * T);

    // 4) row softmax in place
    softmax_rows<<<dim3(B * T), blk, 0, stream>>>(Sb, T);

    // 5) y = P @ V via NT gemm with Vt, K-loop causal-clipped, fp32 out
    gemm_bt<true, false, true><<<dim3(C / BN, T / BM, B), blk, 0, stream>>>(
        Sb, Vt, out, T, C, T, 1.f, (long)T * T, (long)C * T, (long)T * C);
}

// Round 3
// 173.385 us; speedup vs baseline: 1.4769x; 1.2923x over previous
//
#include <hip/hip_runtime.h>
#include <hip/hip_bf16.h>

typedef __attribute__((ext_vector_type(8))) short short8;
typedef __attribute__((ext_vector_type(4))) float f32x4;

// ---------------- helpers ----------------
__device__ __forceinline__ ushort f2b(float f) {
    __hip_bfloat16 h = __float2bfloat16(f);
    return *reinterpret_cast<ushort*>(&h);
}
__device__ __forceinline__ float b2f(ushort u) {
    return __uint_as_float(((unsigned)u) << 16);
}
__device__ __forceinline__ void gload16(const ushort* g, ushort* l) {
    __builtin_amdgcn_global_load_lds(
        (const __attribute__((address_space(1))) void*)g,
        (__attribute__((address_space(3))) void*)l, 16, 0, 0);
}

// ============================================================================
// Ring-pipelined 128x128 NT GEMM, BK=32, 4-slot LDS ring, counted vmcnt.
// 256 threads = 4 waves (2x2), per-wave 64x64 out = 4x4 16x16 frags.
// LDS: 4 slots x (A 8KB + B 8KB) = 64 KB -> 2 blocks/CU.
// st_16x32 subtile layout + bit9->bit5 XOR swizzle (T2), both sides.
// MODE 0 = QKV (bf16 out + bias, W concat N=3072, XCD-chunk swizzle)
// MODE 1 = scores (lower-triangle blocks only, bf16 out, scale, diag mask)
// MODE 2 = PV (fp32 out, K clipped to causal extent, paired-balance grid)
// ============================================================================
template <int MODE>
__global__ __launch_bounds__(256, 2) void gemm_ring(
    const ushort* __restrict__ xb, const ushort* __restrict__ Wcat,
    const float* __restrict__ bk, const float* __restrict__ bq, const float* __restrict__ bv,
    ushort* __restrict__ Kb, ushort* __restrict__ Qb, ushort* __restrict__ Vb,
    ushort* __restrict__ Sb, const ushort* __restrict__ Vt, float* __restrict__ out) {
    constexpr int T = 2048, C = 1024;
    __shared__ ushort smem[32768];  // 64 KB

    const int tid = threadIdx.x;
    const int l = tid & 63, w = tid >> 6;
    const int wm = (w >> 1) * 64, wn = (w & 1) * 64;
    const int lr = l & 15, lk = l >> 4;

    // ---- per-mode geometry ----
    int m0, n0, nt, iblk = 0, jblk = 0, z = 0;
    const ushort *Au, *Bu;
    int ldA, ldB;  // row pitch in elements
    if constexpr (MODE == 0) {
        const int wg = blockIdx.x;                 // 1536
        const int swz = (wg & 7) * 192 + (wg >> 3);  // XCD-chunked (1536%8==0)
        m0 = (swz / 24) * 128; n0 = (swz % 24) * 128;
        Au = xb + (size_t)m0 * C;   ldA = C;
        Bu = Wcat + (size_t)n0 * C; ldB = C;
        nt = 32;
    } else if constexpr (MODE == 1) {
        const int wg = blockIdx.x;                 // 544 = 4*136
        z = wg / 136; const int t136 = wg % 136;
        int i = (int)((sqrtf(8.f * t136 + 1.f) - 1.f) * 0.5f);
        while ((i + 1) * (i + 2) / 2 <= t136) ++i;
        while (i * (i + 1) / 2 > t136) --i;
        const int j = t136 - i * (i + 1) / 2;
        iblk = i; jblk = j;
        m0 = i * 128; n0 = j * 128;
        Au = Qb + (size_t)z * T * C + (size_t)m0 * C; ldA = C;
        Bu = Kb + (size_t)z * T * C + (size_t)n0 * C; ldB = C;
        nt = 32;
    } else {
        const int wg = blockIdx.x;                 // 512
        const int half = wg >> 8, s2 = wg & 255;
        z = s2 >> 6; const int r6 = s2 & 63;
        const int nb = r6 & 7, ii = r6 >> 3;
        const int i = half ? (15 - ii) : ii;       // pair long with short per CU
        iblk = i;
        m0 = i * 128; n0 = nb * 128;
        Au = Sb + (size_t)z * T * T + (size_t)m0 * T; ldA = T;
        Bu = Vt + (size_t)z * C * T + (size_t)n0 * T; ldB = T;
        nt = 4 * (i + 1);
    }

    // ---- staging coords (pre-swizzled source; linear LDS dest) ----
    // unit = 128 rows x 64B = 8KB = 2 issues; subtile 16 rows x 64B = 1KB
    const int srow = w * 16 + (l >> 2);                       // issue0 rows 0..63
    const int scb = ((l & 3) << 4) ^ ((l >= 32) ? 32 : 0);    // swizzled byte col
    const ushort* gA = Au + (size_t)srow * ldA + (scb >> 1);
    const ushort* gB = Bu + (size_t)srow * ldB + (scb >> 1);
    const size_t a64 = (size_t)64 * ldA, b64 = (size_t)64 * ldB;
    // ds_read per-lane base (ushort units), swizzled
    const int LBu = lr * 32 + ((lk << 3) ^ ((lr >= 8) ? 16 : 0));

    f32x4 acc[4][4] = {};

#define STAGE(tt)                                                        \
    {                                                                    \
        const int _s = (tt) & 3; const int _ko = (tt) * 32;              \
        ushort* _d = smem + _s * 8192 + w * 512;                         \
        gload16(gA + _ko,        _d);                                    \
        gload16(gA + a64 + _ko,  _d + 2048);                             \
        gload16(gB + _ko,        _d + 4096);                             \
        gload16(gB + b64 + _ko,  _d + 6144);                             \
    }

    // prologue: 3 tiles in flight, wait for tile 0 (keep newest 8 loads)
    STAGE(0); STAGE(1); STAGE(2);
    asm volatile("s_waitcnt vmcnt(8)" ::: "memory");
    __builtin_amdgcn_s_barrier();
    asm volatile("" ::: "memory");

    for (int t = 0; t < nt; ++t) {
        const int slot = t & 3;
        const ushort* As = smem + slot * 8192 + (wm >> 4) * 512 + LBu;
        const ushort* Bs = smem + slot * 8192 + 4096 + (wn >> 4) * 512 + LBu;
        short8 af[4], bf[4];
#pragma unroll
        for (int q = 0; q < 4; ++q) {
            af[q] = *reinterpret_cast<const short8*>(As + q * 512);
            bf[q] = *reinterpret_cast<const short8*>(Bs + q * 512);
        }
        if (t + 3 < nt) STAGE(t + 3);
        __builtin_amdgcn_s_barrier();
        asm volatile("" ::: "memory");
        __builtin_amdgcn_s_setprio(1);
#pragma unroll
        for (int mf = 0; mf < 4; ++mf)
#pragma unroll
            for (int nf = 0; nf < 4; ++nf)
                acc[mf][nf] = __builtin_amdgcn_mfma_f32_16x16x32_bf16(af[mf], bf[nf], acc[mf][nf], 0, 0, 0);
        __builtin_amdgcn_s_setprio(0);
        const int rem = nt - 2 - t;
        if (rem >= 2)      asm volatile("s_waitcnt vmcnt(8)" ::: "memory");
        else if (rem == 1) asm volatile("s_waitcnt vmcnt(4)" ::: "memory");
        else if (rem == 0) asm volatile("s_waitcnt vmcnt(0)" ::: "memory");
        __builtin_amdgcn_s_barrier();
        asm volatile("" ::: "memory");
    }
#undef STAGE

    // ---- epilogue: C/D frag col = lane&15, row = (lane>>4)*4 + reg ----
    if constexpr (MODE == 0) {
        const int zsel = n0 >> 10;
        ushort* O = (zsel == 0) ? Kb : (zsel == 1) ? Qb : Vb;
        const float* bias = (zsel == 0) ? bk : (zsel == 1) ? bq : bv;
        const int c0 = (n0 & 1023) + wn;
#pragma unroll
        for (int mf = 0; mf < 4; ++mf)
#pragma unroll
            for (int nf = 0; nf < 4; ++nf) {
                const int gc = c0 + nf * 16 + lr;
                const float badd = bias[gc];
#pragma unroll
                for (int rr = 0; rr < 4; ++rr) {
                    const int gr = m0 + wm + mf * 16 + lk * 4 + rr;
                    O[(size_t)gr * C + gc] = f2b(acc[mf][nf][rr] + badd);
                }
            }
    } else if constexpr (MODE == 1) {
        ushort* Sp = Sb + (size_t)z * T * T;
        const bool diag = (iblk == jblk);
#pragma unroll
        for (int mf = 0; mf < 4; ++mf)
#pragma unroll
            for (int nf = 0; nf < 4; ++nf) {
                const int gc = n0 + wn + nf * 16 + lr;
#pragma unroll
                for (int rr = 0; rr < 4; ++rr) {
                    const int gr = m0 + wm + mf * 16 + lk * 4 + rr;
                    if (!diag || gc <= gr)
                        Sp[(size_t)gr * T + gc] = f2b(acc[mf][nf][rr] * 0.03125f);
                }
            }
    } else {
        float* Op = out + (size_t)z * T * C;
#pragma unroll
        for (int mf = 0; mf < 4; ++mf)
#pragma unroll
            for (int nf = 0; nf < 4; ++nf) {
                const int gc = n0 + wn + nf * 16 + lr;
#pragma unroll
                for (int rr = 0; rr < 4; ++rr) {
                    const int gr = m0 + wm + mf * 16 + lk * 4 + rr;
                    Op[(size_t)gr * C + gc] = acc[mf][nf][rr];
                }
            }
    }
}

// ---- fp32 -> bf16 convert, 8 elems/thread ----
__global__ __launch_bounds__(256) void cvt_f32_bf16(const float* __restrict__ in,
                                                    ushort* __restrict__ out, int n8) {
    const int i = blockIdx.x * 256 + threadIdx.x;
    if (i >= n8) return;
    const float4* p = reinterpret_cast<const float4*>(in) + (size_t)i * 2;
    float4 a = p[0], b = p[1];
    ushort o[8] = {f2b(a.x), f2b(a.y), f2b(a.z), f2b(a.w),
                   f2b(b.x), f2b(b.y), f2b(b.z), f2b(b.w)};
    reinterpret_cast<uint4*>(out)[i] = *reinterpret_cast<uint4*>(o);
}

// ---- causal-aware row softmax: row r reads cols<=r, writes [0, next128(r+1)) ----
__global__ __launch_bounds__(256) void softmax_rows(ushort* __restrict__ S, int T) {
    const int g = blockIdx.x;
    const int r = g & (T - 1);
    ushort* p = S + (size_t)g * T;
    const int tid = threadIdx.x;
    const int lane = tid & 63, wave = tid >> 6;
    const int c0 = tid * 8;
    const int n_write = ((r >> 7) + 1) << 7;

    float f[8];
    if (c0 <= r) {
        uint4 raw = *reinterpret_cast<const uint4*>(p + c0);
        ushort* rs = reinterpret_cast<ushort*>(&raw);
#pragma unroll
        for (int j = 0; j < 8; ++j) f[j] = (c0 + j <= r) ? b2f(rs[j]) : -INFINITY;
    } else {
#pragma unroll
        for (int j = 0; j < 8; ++j) f[j] = -INFINITY;
    }

    float mx = f[0];
#pragma unroll
    for (int j = 1; j < 8; ++j) mx = fmaxf(mx, f[j]);
#pragma unroll
    for (int o = 32; o > 0; o >>= 1) mx = fmaxf(mx, __shfl_xor(mx, o));

    __shared__ float redm[4], reds[4];
    if (lane == 0) redm[wave] = mx;
    __syncthreads();
    mx = fmaxf(fmaxf(redm[0], redm[1]), fmaxf(redm[2], redm[3]));

    float e[8], s = 0.f;
#pragma unroll
    for (int j = 0; j < 8; ++j) { e[j] = __expf(f[j] - mx); s += e[j]; }
#pragma unroll
    for (int o = 32; o > 0; o >>= 1) s += __shfl_xor(s, o);
    if (lane == 0) reds[wave] = s;
    __syncthreads();
    s = reds[0] + reds[1] + reds[2] + reds[3];

    const float inv = 1.f / s;
    if (c0 < n_write) {
        ushort outv[8];
#pragma unroll
        for (int j = 0; j < 8; ++j) outv[j] = f2b(e[j] * inv);
        *reinterpret_cast<uint4*>(p + c0) = *reinterpret_cast<uint4*>(outv);
    }
}

// ---- per-batch bf16 transpose: Vt[c][s] = V[s][c] ----
__global__ __launch_bounds__(256) void transpose_bf16(const ushort* __restrict__ V,
                                                      ushort* __restrict__ Vt, int R, int Cc) {
    __shared__ ushort t[64][64 + 8];
    const int z = blockIdx.z;
    const ushort* src = V + (size_t)z * R * Cc;
    ushort* dst = Vt + (size_t)z * R * Cc;
    const int r0 = blockIdx.y * 64, c0 = blockIdx.x * 64;
    const int tid = threadIdx.x;
    const int vec = tid & 7, row = tid >> 3;
#pragma unroll
    for (int p = 0; p < 2; ++p) {
        const int r = row + p * 32;
        uint4 v = *reinterpret_cast<const uint4*>(src + (size_t)(r0 + r) * Cc + c0 + vec * 8);
        *reinterpret_cast<uint4*>(&t[r][vec * 8]) = v;
    }
    __syncthreads();
#pragma unroll
    for (int p = 0; p < 2; ++p) {
        const int r = row + p * 32;
        ushort tmp[8];
#pragma unroll
        for (int j = 0; j < 8; ++j) tmp[j] = t[vec * 8 + j][r];
        *reinterpret_cast<uint4*>(dst + (size_t)(c0 + r) * R + r0 + vec * 8) =
            *reinterpret_cast<uint4*>(tmp);
    }
}

extern "C" void kernel_launch(void* const* d_in, const int* in_sizes, int n_in,
                              void* d_out, int out_size, void* d_ws, size_t ws_size,
                              hipStream_t stream) {
    const float* x  = (const float*)d_in[0];
    const float* Wk = (const float*)d_in[1];
    const float* bk = (const float*)d_in[2];
    const float* Wq = (const float*)d_in[3];
    const float* bq = (const float*)d_in[4];
    const float* Wv = (const float*)d_in[5];
    const float* bv = (const float*)d_in[6];
    float* out = (float*)d_out;

    constexpr int B = 4, T = 2048, C = 1024;
    constexpr size_t BTC = (size_t)B * T * C;  // 8388608

    ushort* Kb = (ushort*)d_ws;
    ushort* Qb = Kb + BTC;
    ushort* Vb = Qb + BTC;
    ushort* Vt = Vb + BTC;
    ushort* Sb = Vt + BTC;                      // B*T*T ushorts
    // aliased into Sb (dead before scores writes; non-causal region never read):
    ushort* xb   = Sb;                          // B*T*C
    ushort* Wcat = Sb + BTC;                    // 3 * C*C (Wk,Wq,Wv contiguous)

    dim3 blk(256);

    // 0) fp32 -> bf16
    cvt_f32_bf16<<<dim3(4096), blk, 0, stream>>>(x, xb, (int)(BTC / 8));
    cvt_f32_bf16<<<dim3(512), blk, 0, stream>>>(Wk, Wcat, C * C / 8);
    cvt_f32_bf16<<<dim3(512), blk, 0, stream>>>(Wq, Wcat + (size_t)C * C, C * C / 8);
    cvt_f32_bf16<<<dim3(512), blk, 0, stream>>>(Wv, Wcat + 2 * (size_t)C * C, C * C / 8);

    // 1) fused QKV projection (N=3072 concat)
    gemm_ring<0><<<dim3(1536), blk, 0, stream>>>(xb, Wcat, bk, bq, bv,
                                                 Kb, Qb, Vb, Sb, Vt, out);

    // 2) V transpose per batch
    transpose_bf16<<<dim3(C / 64, T / 64, B), blk, 0, stream>>>(Vb, Vt, T, C);

    // 3) scores (lower-triangle blocks only)
    gemm_ring<1><<<dim3(544), blk, 0, stream>>>(xb, Wcat, bk, bq, bv,
                                                Kb, Qb, Vb, Sb, Vt, out);

    // 4) causal row softmax
    softmax_rows<<<dim3(B * T), blk, 0, stream>>>(Sb, T);

    // 5) y = P @ V (K clipped to causal extent)
    gemm_ring<2><<<dim3(512), blk, 0, stream>>>(xb, Wcat, bk, bq, bv,
                                                Kb, Qb, Vb, Sb, Vt, out);
}

// Round 4
// 153.710 us; speedup vs baseline: 1.6660x; 1.1280x over previous
//
#include <hip/hip_runtime.h>
#include <hip/hip_bf16.h>

typedef __attribute__((ext_vector_type(8))) short short8;
typedef __attribute__((ext_vector_type(4))) float f32x4;

// ---------------- helpers ----------------
__device__ __forceinline__ ushort f2b(float f) {
    __hip_bfloat16 h = __float2bfloat16(f);
    return *reinterpret_cast<ushort*>(&h);
}
__device__ __forceinline__ float b2f(ushort u) {
    return __uint_as_float(((unsigned)u) << 16);
}
__device__ __forceinline__ void gload16(const ushort* g, ushort* l) {
    __builtin_amdgcn_global_load_lds(
        (const __attribute__((address_space(1))) void*)g,
        (__attribute__((address_space(3))) void*)l, 16, 0, 0);
}

// ============================================================================
// 3-slot ring 128x128 NT GEMM, BK=32, ONE barrier per K-tile, counted vmcnt.
// 256 threads = 4 waves (2x2), per-wave 64x64 out = 4x4 16x16 frags.
// LDS: 3 slots x (A 8KB + B 8KB) = 48 KB -> 3 blocks/CU (12 waves/CU).
// st_16x32 subtile layout + XOR swizzle (T2) both sides (src pre-swizzle).
// MODE 0 = QKV (bf16 K/Q row-major + V transposed into Vt, bias, N=3072)
// MODE 1 = scores (lower-triangle blocks only, bf16 out, scale, diag mask)
// MODE 2 = PV (fp32 out, K clipped to causal extent, paired-balance grid)
// ============================================================================
template <int MODE>
__global__ __launch_bounds__(256, 3) void gemm_ring(
    const ushort* __restrict__ xb, const ushort* __restrict__ Wcat,
    const float* __restrict__ bk, const float* __restrict__ bq, const float* __restrict__ bv,
    ushort* __restrict__ Kb, ushort* __restrict__ Qb, ushort* __restrict__ Vt,
    ushort* __restrict__ Sb, float* __restrict__ out) {
    constexpr int T = 2048, C = 1024;
    __shared__ ushort smem[24576];  // 48 KB

    const int tid = threadIdx.x;
    const int l = tid & 63, w = tid >> 6;
    const int wm = (w >> 1) * 64, wn = (w & 1) * 64;
    const int lr = l & 15, lk = l >> 4;

    // ---- per-mode geometry ----
    int m0, n0, nt, iblk = 0, jblk = 0, z = 0;
    const ushort *Au, *Bu;
    int ldA, ldB;
    if constexpr (MODE == 0) {
        const int wg = blockIdx.x;                   // 1536 = 8*192
        const int swz = (wg & 7) * 192 + (wg >> 3);  // XCD-chunked
        m0 = (swz / 24) * 128; n0 = (swz % 24) * 128;
        Au = xb + (size_t)m0 * C;   ldA = C;
        Bu = Wcat + (size_t)n0 * C; ldB = C;
        nt = 32;
    } else if constexpr (MODE == 1) {
        const int wg0 = blockIdx.x;                  // 544 = 8*68
        const int wg = (wg0 & 7) * 68 + (wg0 >> 3);
        z = wg / 136; const int t136 = wg % 136;
        int i = (int)((sqrtf(8.f * t136 + 1.f) - 1.f) * 0.5f);
        while ((i + 1) * (i + 2) / 2 <= t136) ++i;
        while (i * (i + 1) / 2 > t136) --i;
        const int j = t136 - i * (i + 1) / 2;
        iblk = i; jblk = j;
        m0 = i * 128; n0 = j * 128;
        Au = Qb + (size_t)z * T * C + (size_t)m0 * C; ldA = C;
        Bu = Kb + (size_t)z * T * C + (size_t)m0 * 0 + (size_t)(j * 128) * C; ldB = C;
        nt = 32;
    } else {
        const int wg0 = blockIdx.x;                  // 512 = 8*64
        const int wg = (wg0 & 7) * 64 + (wg0 >> 3);
        const int half = wg >> 8, s2 = wg & 255;
        z = s2 >> 6; const int r6 = s2 & 63;
        const int nb = r6 & 7, ii = r6 >> 3;
        const int i = half ? (15 - ii) : ii;         // pair long with short
        iblk = i;
        m0 = i * 128; n0 = nb * 128;
        Au = Sb + (size_t)z * T * T + (size_t)m0 * T; ldA = T;
        Bu = Vt + (size_t)z * C * T + (size_t)n0 * T; ldB = T;
        nt = 4 * (i + 1);
    }

    // ---- staging coords (pre-swizzled source; linear LDS dest) ----
    const int srow = w * 16 + (l >> 2);                      // issue0 rows 0..63
    const int scb = ((l & 3) << 4) ^ ((l >= 32) ? 32 : 0);   // swizzled byte col
    const ushort* gA = Au + (size_t)srow * ldA + (scb >> 1);
    const ushort* gB = Bu + (size_t)srow * ldB + (scb >> 1);
    const size_t a64 = (size_t)64 * ldA, b64 = (size_t)64 * ldB;
    // ds_read per-lane base (ushort units), swizzled
    const int LBu = lr * 32 + ((lk << 3) ^ ((lr >= 8) ? 16 : 0));

    f32x4 acc[4][4] = {};

#define STAGE(tt, sl)                                                    \
    {                                                                    \
        const int _ko = (tt) * 32;                                       \
        ushort* _d = smem + (sl) * 8192 + w * 512;                       \
        gload16(gA + _ko,        _d);                                    \
        gload16(gA + a64 + _ko,  _d + 2048);                             \
        gload16(gB + _ko,        _d + 4096);                             \
        gload16(gB + b64 + _ko,  _d + 6144);                             \
    }

    // prologue: stage tiles 0,1; wait for tile 0 (4 newest outstanding ok)
    STAGE(0, 0);
    STAGE(1, 1);
    asm volatile("s_waitcnt vmcnt(4)" ::: "memory");
    __builtin_amdgcn_s_barrier();
    asm volatile("" ::: "memory");

    int sc = 0, ss = 2;
    for (int t = 0; t < nt; ++t) {
        const ushort* As = smem + sc * 8192 + (wm >> 4) * 512 + LBu;
        const ushort* Bs = smem + sc * 8192 + 4096 + (wn >> 4) * 512 + LBu;
        short8 af[4], bf[4];
#pragma unroll
        for (int q = 0; q < 4; ++q) {
            af[q] = *reinterpret_cast<const short8*>(As + q * 512);
            bf[q] = *reinterpret_cast<const short8*>(Bs + q * 512);
        }
        if (t + 2 < nt) STAGE(t + 2, ss);
        __builtin_amdgcn_s_setprio(1);
#pragma unroll
        for (int mf = 0; mf < 4; ++mf)
#pragma unroll
            for (int nf = 0; nf < 4; ++nf)
                acc[mf][nf] = __builtin_amdgcn_mfma_f32_16x16x32_bf16(af[mf], bf[nf], acc[mf][nf], 0, 0, 0);
        __builtin_amdgcn_s_setprio(0);
        if (t + 1 < nt) {
            if (t + 2 < nt) asm volatile("s_waitcnt vmcnt(4)" ::: "memory");
            else            asm volatile("s_waitcnt vmcnt(0)" ::: "memory");
            __builtin_amdgcn_s_barrier();
            asm volatile("" ::: "memory");
        }
        sc = (sc == 2) ? 0 : sc + 1;
        ss = (ss == 2) ? 0 : ss + 1;
    }
#undef STAGE

    // ---- epilogue: C/D frag col = lane&15, row = (lane>>4)*4 + reg ----
    if constexpr (MODE == 0) {
        const int zsel = n0 >> 10;
        const int c0 = (n0 & 1023) + wn;
        if (zsel < 2) {
            ushort* O = (zsel == 0) ? Kb : Qb;
            const float* bias = (zsel == 0) ? bk : bq;
#pragma unroll
            for (int mf = 0; mf < 4; ++mf)
#pragma unroll
                for (int nf = 0; nf < 4; ++nf) {
                    const int gc = c0 + nf * 16 + lr;
                    const float badd = bias[gc];
#pragma unroll
                    for (int rr = 0; rr < 4; ++rr) {
                        const int gr = m0 + wm + mf * 16 + lk * 4 + rr;
                        O[(size_t)gr * C + gc] = f2b(acc[mf][nf][rr] + badd);
                    }
                }
        } else {
            // V: write transposed into Vt[z][c][s]; 4 contiguous s per lane = 8B store
            const int zb = (m0 + wm) >> 11;          // whole block same batch
            const int s0 = (m0 + wm) & 2047;
            ushort* Vz = Vt + (size_t)zb * C * T;
#pragma unroll
            for (int mf = 0; mf < 4; ++mf)
#pragma unroll
                for (int nf = 0; nf < 4; ++nf) {
                    const int gc = c0 + nf * 16 + lr;
                    const float badd = bv[gc];
                    const int s = s0 + mf * 16 + lk * 4;
                    ushort tmp[4];
#pragma unroll
                    for (int rr = 0; rr < 4; ++rr) tmp[rr] = f2b(acc[mf][nf][rr] + badd);
                    *reinterpret_cast<uint2*>(Vz + (size_t)gc * T + s) =
                        *reinterpret_cast<uint2*>(tmp);
                }
        }
    } else if constexpr (MODE == 1) {
        ushort* Sp = Sb + (size_t)z * T * T;
        const bool diag = (iblk == jblk);
#pragma unroll
        for (int mf = 0; mf < 4; ++mf)
#pragma unroll
            for (int nf = 0; nf < 4; ++nf) {
                const int gc = n0 + wn + nf * 16 + lr;
#pragma unroll
                for (int rr = 0; rr < 4; ++rr) {
                    const int gr = m0 + wm + mf * 16 + lk * 4 + rr;
                    if (!diag || gc <= gr)
                        Sp[(size_t)gr * T + gc] = f2b(acc[mf][nf][rr] * 0.03125f);
                }
            }
    } else {
        float* Op = out + (size_t)z * T * C;
#pragma unroll
        for (int mf = 0; mf < 4; ++mf)
#pragma unroll
            for (int nf = 0; nf < 4; ++nf) {
                const int gc = n0 + wn + nf * 16 + lr;
#pragma unroll
                for (int rr = 0; rr < 4; ++rr) {
                    const int gr = m0 + wm + mf * 16 + lk * 4 + rr;
                    Op[(size_t)gr * C + gc] = acc[mf][nf][rr];
                }
            }
    }
}

// ---- fused fp32 -> bf16 convert for x, Wk, Wq, Wv (8 elems/thread) ----
__global__ __launch_bounds__(256) void cvt_all(
    const float* __restrict__ x, const float* __restrict__ Wk,
    const float* __restrict__ Wq, const float* __restrict__ Wv,
    ushort* __restrict__ xb, ushort* __restrict__ Wcat) {
    constexpr int C = 1024;
    constexpr int NX = 8388608 / 8, NW = C * C / 8;
    int i = blockIdx.x * 256 + threadIdx.x;
    const float* src; ushort* dst;
    if (i < NX)               { src = x;  dst = xb; }
    else if (i < NX + NW)     { src = Wk; dst = Wcat;                 i -= NX; }
    else if (i < NX + 2 * NW) { src = Wq; dst = Wcat + (size_t)C * C; i -= NX + NW; }
    else                      { src = Wv; dst = Wcat + 2 * (size_t)C * C; i -= NX + 2 * NW; }
    const float4* p = reinterpret_cast<const float4*>(src) + (size_t)i * 2;
    float4 a = p[0], b = p[1];
    ushort o[8] = {f2b(a.x), f2b(a.y), f2b(a.z), f2b(a.w),
                   f2b(b.x), f2b(b.y), f2b(b.z), f2b(b.w)};
    reinterpret_cast<uint4*>(dst)[i] = *reinterpret_cast<uint4*>(o);
}

// ---- causal-aware row softmax: row r reads cols<=r, writes [0, next128(r+1)) ----
__global__ __launch_bounds__(256) void softmax_rows(ushort* __restrict__ S, int T) {
    const int g = blockIdx.x;
    const int r = g & (T - 1);
    ushort* p = S + (size_t)g * T;
    const int tid = threadIdx.x;
    const int lane = tid & 63, wave = tid >> 6;
    const int c0 = tid * 8;
    const int n_write = ((r >> 7) + 1) << 7;

    float f[8];
    if (c0 <= r) {
        uint4 raw = *reinterpret_cast<const uint4*>(p + c0);
        ushort* rs = reinterpret_cast<ushort*>(&raw);
#pragma unroll
        for (int j = 0; j < 8; ++j) f[j] = (c0 + j <= r) ? b2f(rs[j]) : -INFINITY;
    } else {
#pragma unroll
        for (int j = 0; j < 8; ++j) f[j] = -INFINITY;
    }

    float mx = f[0];
#pragma unroll
    for (int j = 1; j < 8; ++j) mx = fmaxf(mx, f[j]);
#pragma unroll
    for (int o = 32; o > 0; o >>= 1) mx = fmaxf(mx, __shfl_xor(mx, o));

    __shared__ float redm[4], reds[4];
    if (lane == 0) redm[wave] = mx;
    __syncthreads();
    mx = fmaxf(fmaxf(redm[0], redm[1]), fmaxf(redm[2], redm[3]));

    float e[8], s = 0.f;
#pragma unroll
    for (int j = 0; j < 8; ++j) { e[j] = __expf(f[j] - mx); s += e[j]; }
#pragma unroll
    for (int o = 32; o > 0; o >>= 1) s += __shfl_xor(s, o);
    if (lane == 0) reds[wave] = s;
    __syncthreads();
    s = reds[0] + reds[1] + reds[2] + reds[3];

    const float inv = 1.f / s;
    if (c0 < n_write) {
        ushort outv[8];
#pragma unroll
        for (int j = 0; j < 8; ++j) outv[j] = f2b(e[j] * inv);
        *reinterpret_cast<uint4*>(p + c0) = *reinterpret_cast<uint4*>(outv);
    }
}

extern "C" void kernel_launch(void* const* d_in, const int* in_sizes, int n_in,
                              void* d_out, int out_size, void* d_ws, size_t ws_size,
                              hipStream_t stream) {
    const float* x  = (const float*)d_in[0];
    const float* Wk = (const float*)d_in[1];
    const float* bk = (const float*)d_in[2];
    const float* Wq = (const float*)d_in[3];
    const float* bq = (const float*)d_in[4];
    const float* Wv = (const float*)d_in[5];
    const float* bv = (const float*)d_in[6];
    float* out = (float*)d_out;

    constexpr int B = 4, T = 2048, C = 1024;
    constexpr size_t BTC = (size_t)B * T * C;  // 8388608

    ushort* Kb = (ushort*)d_ws;
    ushort* Qb = Kb + BTC;
    ushort* Vt = Qb + BTC;                      // V stored transposed [B][C][T]
    ushort* Sb = Vt + BTC;                      // B*T*T ushorts
    // aliased into Sb (dead before scores writes):
    ushort* xb   = Sb;                          // B*T*C
    ushort* Wcat = Sb + BTC;                    // 3 * C*C (Wk,Wq,Wv contiguous)

    dim3 blk(256);

    // 0) fp32 -> bf16 (single fused launch)
    cvt_all<<<dim3(5632), blk, 0, stream>>>(x, Wk, Wq, Wv, xb, Wcat);

    // 1) fused QKV projection (N=3072 concat; V written transposed)
    gemm_ring<0><<<dim3(1536), blk, 0, stream>>>(xb, Wcat, bk, bq, bv,
                                                 Kb, Qb, Vt, Sb, out);

    // 2) scores (lower-triangle blocks only)
    gemm_ring<1><<<dim3(544), blk, 0, stream>>>(xb, Wcat, bk, bq, bv,
                                                Kb, Qb, Vt, Sb, out);

    // 3) causal row softmax
    softmax_rows<<<dim3(B * T), blk, 0, stream>>>(Sb, T);

    // 4) y = P @ V (K clipped to causal extent)
    gemm_ring<2><<<dim3(512), blk, 0, stream>>>(xb, Wcat, bk, bq, bv,
                                                Kb, Qb, Vt, Sb, out);
}

// Round 5
// 145.577 us; speedup vs baseline: 1.7591x; 1.0559x over previous
//
#include <hip/hip_runtime.h>
#include <hip/hip_bf16.h>

typedef __attribute__((ext_vector_type(8))) short short8;
typedef __attribute__((ext_vector_type(4))) float f32x4;

// ---------------- helpers ----------------
__device__ __forceinline__ ushort f2b(float f) {
    __hip_bfloat16 h = __float2bfloat16(f);
    return *reinterpret_cast<ushort*>(&h);
}
__device__ __forceinline__ float b2f(ushort u) {
    return __uint_as_float(((unsigned)u) << 16);
}
__device__ __forceinline__ void gload16(const ushort* g, ushort* l) {
    __builtin_amdgcn_global_load_lds(
        (const __attribute__((address_space(1))) void*)g,
        (__attribute__((address_space(3))) void*)l, 16, 0, 0);
}

// ============================================================================
// QKV: 256x128-tile NT GEMM, BK=64, double-buffered with counted vmcnt.
// 512 thr = 8 waves (2M x 4N), per-wave 128x32 out (acc[8][2]).
// LDS per buf: A 256x64 (32KB, 2 k-half units of 16KB) + B 128x64 (16KB,
// 2 k-half units of 8KB) = 48KB; 2 bufs = 96KB -> 1 block/CU.
// Per K-tile: 2 phases (k-half); per phase: ds_read 10xb128, stage next
// tile's matching k-half units (3 gloads/thread), 16 MFMA. Boundary waits
// vmcnt(3) (never 0 in steady state). st_16x32 swizzle, 0 bank conflicts.
// Grid 768 = 32m x 24n = exactly 3 full rounds; XCD-bijective swizzle.
// ============================================================================
__global__ __launch_bounds__(512, 1) void qkv_gemm256(
    const ushort* __restrict__ xb, const ushort* __restrict__ Wcat,
    const float* __restrict__ bk, const float* __restrict__ bq, const float* __restrict__ bv,
    ushort* __restrict__ Kb, ushort* __restrict__ Qb, ushort* __restrict__ Vt) {
    constexpr int T = 2048, C = 1024, K = 1024, NT = 16;
    __shared__ ushort smem[49152];  // 96 KB

    const int tid = threadIdx.x;
    const int l = tid & 63, w = tid >> 6;
    const int wm = (w >> 2) * 128, wn = (w & 3) * 32;
    const int lr = l & 15, lk = l >> 4;

    const int b = blockIdx.x;                  // 768 = 8*96
    const int wg = (b & 7) * 96 + (b >> 3);    // XCD-bijective
    const int m0 = (wg / 24) * 256, n0 = (wg % 24) * 128;

    // staging coords (pre-swizzled source; linear LDS dest)
    const int srow = w * 16 + (l >> 2);                      // 0..127
    const int scb = ((l & 3) << 4) ^ ((l & 32) ? 32 : 0);    // swizzled byte col
    const ushort* gA = xb + (size_t)(m0 + srow) * K + (scb >> 1);
    const ushort* gB = Wcat + (size_t)(n0 + srow) * K + (scb >> 1);

    // LDS offsets (ushort units): buf d at d*24576.
    // Within buf: Ak(ks) at ks*12288 (16KB each), Bk(ks) at 8192 + ks*12288 (8KB each)
    const int LB = lr * 32 + ((lk << 3) ^ ((lr >= 8) ? 16 : 0));

    f32x4 acc[8][2] = {};

#define STAGEQ(u1, ks)                                                    \
    {                                                                     \
        ushort* _base = smem + ((u1) & 1) * 24576 + (ks) * 12288;         \
        const int _ko = (u1) * 64 + (ks) * 32;                            \
        ushort* _da = _base + w * 512;                                    \
        gload16(gA + _ko, _da);                                           \
        gload16(gA + (size_t)128 * K + _ko, _da + 4096);                  \
        gload16(gB + _ko, _base + 8192 + w * 512);                        \
    }

    STAGEQ(0, 0);
    STAGEQ(0, 1);

    for (int u = 0; u < NT; ++u) {
        const ushort* buf = smem + (u & 1) * 24576;
        // ---- phase 0 (k-half 0) ----
        asm volatile("s_waitcnt vmcnt(3)" ::: "memory");
        __builtin_amdgcn_s_barrier();
        asm volatile("" ::: "memory");
        {
            const ushort* Ab = buf + (wm >> 4) * 512 + LB;
            const ushort* Bb = buf + 8192 + (wn >> 4) * 512 + LB;
            short8 a[8], bf2[2];
#pragma unroll
            for (int f = 0; f < 8; ++f) a[f] = *reinterpret_cast<const short8*>(Ab + f * 512);
            bf2[0] = *reinterpret_cast<const short8*>(Bb);
            bf2[1] = *reinterpret_cast<const short8*>(Bb + 512);
            if (u + 1 < NT) STAGEQ(u + 1, 0);
            __builtin_amdgcn_s_setprio(1);
#pragma unroll
            for (int f = 0; f < 8; ++f)
#pragma unroll
                for (int g = 0; g < 2; ++g)
                    acc[f][g] = __builtin_amdgcn_mfma_f32_16x16x32_bf16(a[f], bf2[g], acc[f][g], 0, 0, 0);
            __builtin_amdgcn_s_setprio(0);
        }
        // ---- phase 1 (k-half 1) ----
        if (u + 1 < NT) asm volatile("s_waitcnt vmcnt(3)" ::: "memory");
        else            asm volatile("s_waitcnt vmcnt(0)" ::: "memory");
        __builtin_amdgcn_s_barrier();
        asm volatile("" ::: "memory");
        {
            const ushort* Ab = buf + 12288 + (wm >> 4) * 512 + LB;
            const ushort* Bb = buf + 12288 + 8192 + (wn >> 4) * 512 + LB;
            short8 a[8], bf2[2];
#pragma unroll
            for (int f = 0; f < 8; ++f) a[f] = *reinterpret_cast<const short8*>(Ab + f * 512);
            bf2[0] = *reinterpret_cast<const short8*>(Bb);
            bf2[1] = *reinterpret_cast<const short8*>(Bb + 512);
            if (u + 1 < NT) STAGEQ(u + 1, 1);
            __builtin_amdgcn_s_setprio(1);
#pragma unroll
            for (int f = 0; f < 8; ++f)
#pragma unroll
                for (int g = 0; g < 2; ++g)
                    acc[f][g] = __builtin_amdgcn_mfma_f32_16x16x32_bf16(a[f], bf2[g], acc[f][g], 0, 0, 0);
            __builtin_amdgcn_s_setprio(0);
        }
    }
#undef STAGEQ

    // ---- epilogue ----
    const int zsel = n0 >> 10;
    const int c0 = (n0 & 1023) + wn;
    if (zsel < 2) {
        ushort* O = (zsel == 0) ? Kb : Qb;
        const float* bias = (zsel == 0) ? bk : bq;
#pragma unroll
        for (int f = 0; f < 8; ++f)
#pragma unroll
            for (int g = 0; g < 2; ++g) {
                const int gc = c0 + g * 16 + lr;
                const float badd = bias[gc];
#pragma unroll
                for (int rr = 0; rr < 4; ++rr) {
                    const int gr = m0 + wm + f * 16 + lk * 4 + rr;
                    O[(size_t)gr * C + gc] = f2b(acc[f][g][rr] + badd);
                }
            }
    } else {
        const int zb = (m0 + wm) >> 11;
        const int s0 = (m0 + wm) & 2047;
        ushort* Vz = Vt + (size_t)zb * C * T;
#pragma unroll
        for (int f = 0; f < 8; ++f)
#pragma unroll
            for (int g = 0; g < 2; ++g) {
                const int gc = c0 + g * 16 + lr;
                const float badd = bv[gc];
                const int s = s0 + f * 16 + lk * 4;
                ushort tmp[4];
#pragma unroll
                for (int rr = 0; rr < 4; ++rr) tmp[rr] = f2b(acc[f][g][rr] + badd);
                *reinterpret_cast<uint2*>(Vz + (size_t)gc * T + s) =
                    *reinterpret_cast<uint2*>(tmp);
            }
    }
}

// ============================================================================
// 3-slot ring 128x128 NT GEMM (unchanged from r4) for scores / PV.
// ============================================================================
template <int MODE>
__global__ __launch_bounds__(256, 3) void gemm_ring(
    const ushort* __restrict__ Kb, const ushort* __restrict__ Qb,
    const ushort* __restrict__ Vt, ushort* __restrict__ Sb, float* __restrict__ out) {
    constexpr int T = 2048, C = 1024;
    __shared__ ushort smem[24576];  // 48 KB

    const int tid = threadIdx.x;
    const int l = tid & 63, w = tid >> 6;
    const int wm = (w >> 1) * 64, wn = (w & 1) * 64;
    const int lr = l & 15, lk = l >> 4;

    int m0, n0, nt, iblk = 0, jblk = 0, z = 0;
    const ushort *Au, *Bu;
    int ldA, ldB;
    if constexpr (MODE == 1) {
        const int wg0 = blockIdx.x;                  // 544 = 8*68
        const int wg = (wg0 & 7) * 68 + (wg0 >> 3);
        z = wg / 136; const int t136 = wg % 136;
        int i = (int)((sqrtf(8.f * t136 + 1.f) - 1.f) * 0.5f);
        while ((i + 1) * (i + 2) / 2 <= t136) ++i;
        while (i * (i + 1) / 2 > t136) --i;
        const int j = t136 - i * (i + 1) / 2;
        iblk = i; jblk = j;
        m0 = i * 128; n0 = j * 128;
        Au = Qb + (size_t)z * T * C + (size_t)m0 * C; ldA = C;
        Bu = Kb + (size_t)z * T * C + (size_t)n0 * C; ldB = C;
        nt = 32;
    } else {
        const int wg0 = blockIdx.x;                  // 512 = 8*64
        const int wg = (wg0 & 7) * 64 + (wg0 >> 3);
        const int half = wg >> 8, s2 = wg & 255;
        z = s2 >> 6; const int r6 = s2 & 63;
        const int nb = r6 & 7, ii = r6 >> 3;
        const int i = half ? (15 - ii) : ii;
        iblk = i;
        m0 = i * 128; n0 = nb * 128;
        Au = Sb + (size_t)z * T * T + (size_t)m0 * T; ldA = T;
        Bu = Vt + (size_t)z * C * T + (size_t)n0 * T; ldB = T;
        nt = 4 * (i + 1);
    }

    const int srow = w * 16 + (l >> 2);
    const int scb = ((l & 3) << 4) ^ ((l >= 32) ? 32 : 0);
    const ushort* gA = Au + (size_t)srow * ldA + (scb >> 1);
    const ushort* gB = Bu + (size_t)srow * ldB + (scb >> 1);
    const size_t a64 = (size_t)64 * ldA, b64 = (size_t)64 * ldB;
    const int LBu = lr * 32 + ((lk << 3) ^ ((lr >= 8) ? 16 : 0));

    f32x4 acc[4][4] = {};

#define STAGE(tt, sl)                                                    \
    {                                                                    \
        const int _ko = (tt) * 32;                                       \
        ushort* _d = smem + (sl) * 8192 + w * 512;                       \
        gload16(gA + _ko,        _d);                                    \
        gload16(gA + a64 + _ko,  _d + 2048);                             \
        gload16(gB + _ko,        _d + 4096);                             \
        gload16(gB + b64 + _ko,  _d + 6144);                             \
    }

    STAGE(0, 0);
    STAGE(1, 1);
    asm volatile("s_waitcnt vmcnt(4)" ::: "memory");
    __builtin_amdgcn_s_barrier();
    asm volatile("" ::: "memory");

    int sc = 0, ss = 2;
    for (int t = 0; t < nt; ++t) {
        const ushort* As = smem + sc * 8192 + (wm >> 4) * 512 + LBu;
        const ushort* Bs = smem + sc * 8192 + 4096 + (wn >> 4) * 512 + LBu;
        short8 af[4], bf[4];
#pragma unroll
        for (int q = 0; q < 4; ++q) {
            af[q] = *reinterpret_cast<const short8*>(As + q * 512);
            bf[q] = *reinterpret_cast<const short8*>(Bs + q * 512);
        }
        if (t + 2 < nt) STAGE(t + 2, ss);
        __builtin_amdgcn_s_setprio(1);
#pragma unroll
        for (int mf = 0; mf < 4; ++mf)
#pragma unroll
            for (int nf = 0; nf < 4; ++nf)
                acc[mf][nf] = __builtin_amdgcn_mfma_f32_16x16x32_bf16(af[mf], bf[nf], acc[mf][nf], 0, 0, 0);
        __builtin_amdgcn_s_setprio(0);
        if (t + 1 < nt) {
            if (t + 2 < nt) asm volatile("s_waitcnt vmcnt(4)" ::: "memory");
            else            asm volatile("s_waitcnt vmcnt(0)" ::: "memory");
            __builtin_amdgcn_s_barrier();
            asm volatile("" ::: "memory");
        }
        sc = (sc == 2) ? 0 : sc + 1;
        ss = (ss == 2) ? 0 : ss + 1;
    }
#undef STAGE

    if constexpr (MODE == 1) {
        ushort* Sp = Sb + (size_t)z * T * T;
        const bool diag = (iblk == jblk);
#pragma unroll
        for (int mf = 0; mf < 4; ++mf)
#pragma unroll
            for (int nf = 0; nf < 4; ++nf) {
                const int gc = n0 + wn + nf * 16 + lr;
#pragma unroll
                for (int rr = 0; rr < 4; ++rr) {
                    const int gr = m0 + wm + mf * 16 + lk * 4 + rr;
                    if (!diag || gc <= gr)
                        Sp[(size_t)gr * T + gc] = f2b(acc[mf][nf][rr] * 0.03125f);
                }
            }
    } else {
        float* Op = out + (size_t)z * T * C;
#pragma unroll
        for (int mf = 0; mf < 4; ++mf)
#pragma unroll
            for (int nf = 0; nf < 4; ++nf) {
                const int gc = n0 + wn + nf * 16 + lr;
#pragma unroll
                for (int rr = 0; rr < 4; ++rr) {
                    const int gr = m0 + wm + mf * 16 + lk * 4 + rr;
                    Op[(size_t)gr * C + gc] = acc[mf][nf][rr];
                }
            }
    }
}

// ---- fused fp32 -> bf16 convert for x, Wk, Wq, Wv ----
__global__ __launch_bounds__(256) void cvt_all(
    const float* __restrict__ x, const float* __restrict__ Wk,
    const float* __restrict__ Wq, const float* __restrict__ Wv,
    ushort* __restrict__ xb, ushort* __restrict__ Wcat) {
    constexpr int C = 1024;
    constexpr int NX = 8388608 / 8, NW = C * C / 8;
    int i = blockIdx.x * 256 + threadIdx.x;
    const float* src; ushort* dst;
    if (i < NX)               { src = x;  dst = xb; }
    else if (i < NX + NW)     { src = Wk; dst = Wcat;                 i -= NX; }
    else if (i < NX + 2 * NW) { src = Wq; dst = Wcat + (size_t)C * C; i -= NX + NW; }
    else                      { src = Wv; dst = Wcat + 2 * (size_t)C * C; i -= NX + 2 * NW; }
    const float4* p = reinterpret_cast<const float4*>(src) + (size_t)i * 2;
    float4 a = p[0], b = p[1];
    ushort o[8] = {f2b(a.x), f2b(a.y), f2b(a.z), f2b(a.w),
                   f2b(b.x), f2b(b.y), f2b(b.z), f2b(b.w)};
    reinterpret_cast<uint4*>(dst)[i] = *reinterpret_cast<uint4*>(o);
}

// ---- causal-aware row softmax ----
__global__ __launch_bounds__(256) void softmax_rows(ushort* __restrict__ S, int T) {
    const int g = blockIdx.x;
    const int r = g & (T - 1);
    ushort* p = S + (size_t)g * T;
    const int tid = threadIdx.x;
    const int lane = tid & 63, wave = tid >> 6;
    const int c0 = tid * 8;
    const int n_write = ((r >> 7) + 1) << 7;

    float f[8];
    if (c0 <= r) {
        uint4 raw = *reinterpret_cast<const uint4*>(p + c0);
        ushort* rs = reinterpret_cast<ushort*>(&raw);
#pragma unroll
        for (int j = 0; j < 8; ++j) f[j] = (c0 + j <= r) ? b2f(rs[j]) : -INFINITY;
    } else {
#pragma unroll
        for (int j = 0; j < 8; ++j) f[j] = -INFINITY;
    }

    float mx = f[0];
#pragma unroll
    for (int j = 1; j < 8; ++j) mx = fmaxf(mx, f[j]);
#pragma unroll
    for (int o = 32; o > 0; o >>= 1) mx = fmaxf(mx, __shfl_xor(mx, o));

    __shared__ float redm[4], reds[4];
    if (lane == 0) redm[wave] = mx;
    __syncthreads();
    mx = fmaxf(fmaxf(redm[0], redm[1]), fmaxf(redm[2], redm[3]));

    float e[8], s = 0.f;
#pragma unroll
    for (int j = 0; j < 8; ++j) { e[j] = __expf(f[j] - mx); s += e[j]; }
#pragma unroll
    for (int o = 32; o > 0; o >>= 1) s += __shfl_xor(s, o);
    if (lane == 0) reds[wave] = s;
    __syncthreads();
    s = reds[0] + reds[1] + reds[2] + reds[3];

    const float inv = 1.f / s;
    if (c0 < n_write) {
        ushort outv[8];
#pragma unroll
        for (int j = 0; j < 8; ++j) outv[j] = f2b(e[j] * inv);
        *reinterpret_cast<uint4*>(p + c0) = *reinterpret_cast<uint4*>(outv);
    }
}

extern "C" void kernel_launch(void* const* d_in, const int* in_sizes, int n_in,
                              void* d_out, int out_size, void* d_ws, size_t ws_size,
                              hipStream_t stream) {
    const float* x  = (const float*)d_in[0];
    const float* Wk = (const float*)d_in[1];
    const float* bk = (const float*)d_in[2];
    const float* Wq = (const float*)d_in[3];
    const float* bq = (const float*)d_in[4];
    const float* Wv = (const float*)d_in[5];
    const float* bv = (const float*)d_in[6];
    float* out = (float*)d_out;

    constexpr int B = 4, T = 2048, C = 1024;
    constexpr size_t BTC = (size_t)B * T * C;  // 8388608

    ushort* Kb = (ushort*)d_ws;
    ushort* Qb = Kb + BTC;
    ushort* Vt = Qb + BTC;                      // V stored transposed [B][C][T]
    ushort* Sb = Vt + BTC;                      // B*T*T ushorts
    ushort* xb   = Sb;                          // aliased (dead before scores)
    ushort* Wcat = Sb + BTC;

    dim3 blk(256);

    // 0) fp32 -> bf16 (single fused launch)
    cvt_all<<<dim3(5632), blk, 0, stream>>>(x, Wk, Wq, Wv, xb, Wcat);

    // 1) fused QKV projection, 256x128 tiles, counted-vmcnt dbuf
    qkv_gemm256<<<dim3(768), dim3(512), 0, stream>>>(xb, Wcat, bk, bq, bv, Kb, Qb, Vt);

    // 2) scores (lower-triangle blocks only)
    gemm_ring<1><<<dim3(544), blk, 0, stream>>>(Kb, Qb, Vt, Sb, out);

    // 3) causal row softmax
    softmax_rows<<<dim3(B * T), blk, 0, stream>>>(Sb, T);

    // 4) y = P @ V (K clipped to causal extent)
    gemm_ring<2><<<dim3(512), blk, 0, stream>>>(Kb, Qb, Vt, Sb, out);
}